// Round 2
// baseline (2221.409 us; speedup 1.0000x reference)
//
#include <hip/hip_runtime.h>

#define T_STEPS 512
#define BATCH   128
#define SDIM    1024
#define ODIM    256
#define NWG     80            // 64 g1 (8 groups x 8 producers) + 16 g2 (8 groups x 2)
#define NG1     64
#define NTHR    512           // 8 waves

typedef __attribute__((ext_vector_type(8))) short bf16x8;
typedef __attribute__((ext_vector_type(4))) float f32x4;
typedef __attribute__((ext_vector_type(4))) unsigned int u32x4;
typedef __attribute__((ext_vector_type(2))) unsigned int u32x2;

// ws layout (bytes)
#define WR_OFF   0                          // ushort[1024*1024]  2 MB (w_r bf16)
#define WO_OFF   (2u*1024*1024)             // ushort[256*1024] 512 KB (w_o bf16)
#define TH_OFF   (WO_OFF + 512u*1024)       // 4 x 512 KB tagged-slot th buffers
#define SLOTS_PER_BUF 32768u                // 128 batch x 256 slots (16 B each)
#define FLAG_OFF (TH_OFF + 4u*SLOTS_PER_BUF*16u)   // unsigned flags[NWG], 64 B apart
#define FLAG_STRIDE 16

#define LDS_ROW  1032                       // 1024 shorts + 16 B pad per row

// Tagged slot (16 B): { 4 x bf16 th (8 B) | u32 step-tag | u32 pad }.
// Slot index within a buffer: b*256 + (j>>2)  (b = global batch row, j = state idx).
// One aligned dwordx4 sc1 store publishes data+tag atomically at L3; consumers
// poll the tag embedded in the data itself -> the flag round trip disappears.

__device__ __forceinline__ unsigned short f2bf(float f) {
    union { float f; unsigned u; } v; v.f = f;
    unsigned r = v.u + 0x7fffu + ((v.u >> 16) & 1u);   // round-to-nearest-even
    return (unsigned short)(r >> 16);
}

// sc1 (device-coherent) 16 B ops: bypass per-XCD L2, serviced at L3.
#define LOAD16_SC1(d, p, imm) \
    asm volatile("global_load_dwordx4 %0, %1, off offset:" #imm " sc0 sc1" \
                 : "=v"(d) : "v"(p))
#define STORE16_SC1(p, v) \
    asm volatile("global_store_dwordx4 %0, %1, off sc0 sc1" :: "v"(p), "v"(v) : "memory")
#define WAIT_HOLD8(a,b,c,d,e,f,g,h)                                    \
    asm volatile("s_waitcnt vmcnt(0)"                                  \
                 : "+v"(a), "+v"(b), "+v"(c), "+v"(d),                 \
                   "+v"(e), "+v"(f), "+v"(g), "+v"(h) :: "memory")

__device__ __forceinline__ void st_sc1_u16(unsigned short* p, unsigned short v) {
    __hip_atomic_store(p, v, __ATOMIC_RELAXED, __HIP_MEMORY_SCOPE_AGENT);
}
__device__ __forceinline__ unsigned ld_flag(const unsigned* p) {
    return __hip_atomic_load(p, __ATOMIC_RELAXED, __HIP_MEMORY_SCOPE_AGENT);
}
__device__ __forceinline__ void post_flag(unsigned* p, unsigned v) {
    __hip_atomic_store(p, v, __ATOMIC_RELAXED, __HIP_MEMORY_SCOPE_AGENT);
}

// Stage one group's [16 x 1024] th tile into LDS, polling embedded tags.
// 512 threads x 8 slots (16 B each). Retries until all 8 tags == tg.
#define STAGE_RETRY(sp, tg, d0,d1,d2,d3,d4,d5,d6,d7)                   \
    for (;;) {                                                         \
        LOAD16_SC1(d0, sp, 0);                                         \
        LOAD16_SC1(d1, sp, 512);                                       \
        LOAD16_SC1(d2, sp, 1024);                                      \
        LOAD16_SC1(d3, sp, 1536);                                      \
        LOAD16_SC1(d4, sp, 2048);                                      \
        LOAD16_SC1(d5, sp, 2560);                                      \
        LOAD16_SC1(d6, sp, 3072);                                      \
        LOAD16_SC1(d7, sp, 3584);                                      \
        WAIT_HOLD8(d0, d1, d2, d3, d4, d5, d6, d7);                    \
        unsigned bad = (d0[2]^(tg)) | (d1[2]^(tg)) | (d2[2]^(tg)) |    \
                       (d3[2]^(tg)) | (d4[2]^(tg)) | (d5[2]^(tg)) |    \
                       (d6[2]^(tg)) | (d7[2]^(tg));                    \
        if (!bad) break;                                               \
    }
#define LDS_PUT8(ldst, d0,d1,d2,d3,d4,d5,d6,d7)                        \
    do {                                                               \
        *(u32x2*)((ldst) + 0*128) = (u32x2){d0[0], d0[1]};             \
        *(u32x2*)((ldst) + 1*128) = (u32x2){d1[0], d1[1]};             \
        *(u32x2*)((ldst) + 2*128) = (u32x2){d2[0], d2[1]};             \
        *(u32x2*)((ldst) + 3*128) = (u32x2){d3[0], d3[1]};             \
        *(u32x2*)((ldst) + 4*128) = (u32x2){d4[0], d4[1]};             \
        *(u32x2*)((ldst) + 5*128) = (u32x2){d5[0], d5[1]};             \
        *(u32x2*)((ldst) + 6*128) = (u32x2){d6[0], d6[1]};             \
        *(u32x2*)((ldst) + 7*128) = (u32x2){d7[0], d7[1]};             \
    } while (0)

__global__ __launch_bounds__(NTHR, 2) void trnn_persistent(
    const float* __restrict__ x, const float* __restrict__ h_init,
    const float* __restrict__ w_r, const float* __restrict__ b_r,
    const float* __restrict__ w_o, const float* __restrict__ b_o,
    float* __restrict__ out, char* __restrict__ ws)
{
    unsigned short* wr_bf = (unsigned short*)(ws + WR_OFF);
    unsigned short* wo_bf = (unsigned short*)(ws + WO_OFF);
    u32x4*          thb   = (u32x4*)(ws + TH_OFF);
    unsigned*       flags = (unsigned*)(ws + FLAG_OFF);

    __shared__ unsigned short lds_th[16 * LDS_ROW];   // 33 KB

    const int wg   = blockIdx.x;
    const int tid  = threadIdx.x;
    const int gtid = wg * NTHR + tid;
    const int gstr = NWG * NTHR;

    // ---- init: bf16 weights; th_0 tagged slots (tag 0) into buffer 0 ----
    for (int i = gtid; i < SDIM * SDIM; i += gstr) st_sc1_u16(&wr_bf[i], f2bf(w_r[i]));
    for (int i = gtid; i < ODIM * SDIM; i += gstr) st_sc1_u16(&wo_bf[i], f2bf(w_o[i]));
    for (int i = gtid; i < (int)SLOTS_PER_BUF; i += gstr) {
        const int b = i >> 8, j4 = i & 255;
        const f32x4 hv4 = *(const f32x4*)&h_init[b * SDIM + j4 * 4];
        unsigned p0 = (unsigned)f2bf(tanhf(hv4[0])) | ((unsigned)f2bf(tanhf(hv4[1])) << 16);
        unsigned p1 = (unsigned)f2bf(tanhf(hv4[2])) | ((unsigned)f2bf(tanhf(hv4[3])) << 16);
        u32x4 sv = {p0, p1, 0u, 0u};
        u32x4* dst = thb + ((b >> 4) * 4096 + (b & 15) * 256 + j4);
        STORE16_SC1(dst, sv);
    }

    // ---- global barrier after init (once) ----
    {
        asm volatile("s_waitcnt vmcnt(0)" ::: "memory");
        __syncthreads();
        if (tid == 0) post_flag(&flags[wg * FLAG_STRIDE], 1u);
        if (tid < NWG) {
            while (ld_flag(&flags[tid * FLAG_STRIDE]) < 1u) {}
        }
        __syncthreads();
    }

    const int lane = tid & 63;
    const int wv   = tid >> 6;          // wave 0..7
    const int row  = lane & 15;
    const int quad = lane >> 4;

    const bool is_g1 = (wg < NG1);
    const int g  = is_g1 ? (wg >> 3) : ((wg - NG1) >> 1);
    const int p  = is_g1 ? (wg & 7)  : ((wg - NG1) & 1);
    const int jb = p * 128 + wv * 16;   // this wave's j (or o) base

    // ---- weight-stationary fragments: w[jb+row][k], 128 regs/lane (AGPRs) ----
    const unsigned short* bsrc =
        (is_g1 ? wr_bf + (jb + row) * SDIM
               : wo_bf + (jb + row) * SDIM) + quad * 8;
    bf16x8 bw[32];
    #pragma unroll
    for (int kk = 0; kk < 32; ++kk) bw[kk] = *(const bf16x8*)(bsrc + kk * 32);

    // staging map: thread -> row r_st, slot cols c0 + 32k (j = 4*col)
    const int r_st = tid >> 5;
    const int c0   = tid & 31;
    unsigned short* ldst = &lds_th[r_st * LDS_ROW + c0 * 4];
    const u32x4* stage_base = thb + (g * 4096 + r_st * 256 + c0);
    const unsigned short* arow = &lds_th[row * LDS_ROW + quad * 8];

    if (is_g1) {
        const int j0 = jb + quad * 4;           // 4 consecutive output j
        const int gb = g * 16 + row;            // global batch row
        f32x4 hv = *(const f32x4*)&h_init[gb * SDIM + j0];   // h lives in regs
        const f32x4 brv = *(const f32x4*)&b_r[j0];
        u32x4* slotp = thb + (g * 4096 + row * 256 + p * 32 + wv * 4 + quad);

        for (int t = 0; t < T_STEPS; ++t) {
            // lagged g2 anti-dep: buffer we overwrite this iter held th_{t-3}
            if (tid < 2 && t >= 3) {
                const unsigned tgt = (unsigned)(t - 1);
                while (ld_flag(&flags[(NG1 + g * 2 + tid) * FLAG_STRIDE]) < tgt) {}
            }
            // stage th_t by polling embedded tags (no flags on this path)
            const u32x4* sp = stage_base + (t & 3) * SLOTS_PER_BUF;
            const unsigned tg = (unsigned)t;
            u32x4 d0, d1, d2, d3, d4, d5, d6, d7;
            STAGE_RETRY(sp, tg, d0, d1, d2, d3, d4, d5, d6, d7);
            LDS_PUT8(ldst, d0, d1, d2, d3, d4, d5, d6, d7);
            __syncthreads();

            // D[j][b] = sum_k w[j][k] th[b][k]
            f32x4 acc = {0.f, 0.f, 0.f, 0.f};
            #pragma unroll
            for (int kk = 0; kk < 32; ++kk) {
                bf16x8 tf = *(const bf16x8*)(arow + kk * 32);
                acc = __builtin_amdgcn_mfma_f32_16x16x32_bf16(bw[kk], tf, acc, 0, 0, 0);
            }
            __syncthreads();   // reads done -> next iter may overwrite LDS

            // h' = 0.75 h + 0.25 (th w_r^T + b_r); publish tagged th' slot
            f32x4 hn;
            #pragma unroll
            for (int r = 0; r < 4; ++r)
                hn[r] = 0.75f * hv[r] + 0.25f * (acc[r] + brv[r]);
            hv = hn;
            unsigned p0 = (unsigned)f2bf(tanhf(hn[0])) | ((unsigned)f2bf(tanhf(hn[1])) << 16);
            unsigned p1 = (unsigned)f2bf(tanhf(hn[2])) | ((unsigned)f2bf(tanhf(hn[3])) << 16);
            u32x4 sv = {p0, p1, (unsigned)(t + 1), 0u};
            STORE16_SC1(slotp + ((t + 1) & 3) * SLOTS_PER_BUF, sv);
            // no drain, no flag post: consumers poll the tags directly
        }
    } else {
        const int o0 = jb + quad * 4;           // 4 consecutive output o
        const int gb = g * 16 + row;
        const f32x4 bov = *(const f32x4*)&b_o[o0];
        if (tid == 0) post_flag(&flags[wg * FLAG_STRIDE], 2u);

        for (int t = 1; t <= T_STEPS; ++t) {
            const int xbase = (t - 1) * BATCH * ODIM + gb * ODIM + o0;
            const f32x4 xv = *(const f32x4*)&x[xbase];   // flag-independent
            const u32x4* sp = stage_base + (t & 3) * SLOTS_PER_BUF;
            const unsigned tg = (unsigned)t;
            u32x4 d0, d1, d2, d3, d4, d5, d6, d7;
            STAGE_RETRY(sp, tg, d0, d1, d2, d3, d4, d5, d6, d7);
            LDS_PUT8(ldst, d0, d1, d2, d3, d4, d5, d6, d7);
            __syncthreads();
            // whole WG has read th_t -> post read-done flag before compute
            if (tid == 0) post_flag(&flags[wg * FLAG_STRIDE], (unsigned)(t + 2));

            f32x4 acc = {0.f, 0.f, 0.f, 0.f};
            #pragma unroll
            for (int kk = 0; kk < 32; ++kk) {
                bf16x8 tf = *(const bf16x8*)(arow + kk * 32);
                acc = __builtin_amdgcn_mfma_f32_16x16x32_bf16(bw[kk], tf, acc, 0, 0, 0);
            }
            __syncthreads();   // protect LDS before next iter's writes

            f32x4 ov;
            #pragma unroll
            for (int r = 0; r < 4; ++r) ov[r] = acc[r] + bov[r] - xv[r];
            *(f32x4*)&out[xbase] = ov;           // coalesced 16 B store
        }
    }
}

extern "C" void kernel_launch(void* const* d_in, const int* in_sizes, int n_in,
                              void* d_out, int out_size, void* d_ws, size_t ws_size,
                              hipStream_t stream) {
    const float* x      = (const float*)d_in[0];
    const float* h_init = (const float*)d_in[1];
    const float* w_r    = (const float*)d_in[2];
    const float* b_r    = (const float*)d_in[3];
    const float* w_o    = (const float*)d_in[4];
    const float* b_o    = (const float*)d_in[5];
    float* out = (float*)d_out;
    char*  ws  = (char*)d_ws;

    // zero the barrier/read flags (ws is poisoned 0xAA before every launch;
    // th tag-slots need no reset: poison never equals a valid step tag)
    (void)hipMemsetAsync(ws + FLAG_OFF, 0, NWG * 64, stream);

    trnn_persistent<<<dim3(NWG), dim3(NTHR), 0, stream>>>(
        x, h_init, w_r, b_r, w_o, b_o, out, ws);
}